// Round 1
// 334.595 us; speedup vs baseline: 1.0143x; 1.0143x over previous
//
#include <hip/hip_runtime.h>
#include <hip/hip_bf16.h>
#include <hip/hip_fp16.h>
#include <math.h>

#define NF 256
#define NH 64
#define NC 16
#define NBMAX 512      // max buckets (N/256 <= 512 -> N <= 131072)
#define BTILE 8192     // edges per k_bin block

typedef __attribute__((ext_vector_type(8))) __bf16 bf16x8;
typedef __attribute__((ext_vector_type(4))) float f32x4;
typedef __attribute__((ext_vector_type(8))) short short8;

__device__ __forceinline__ unsigned short f2bf(float v) {   // RNE fp32->bf16
    unsigned u = __float_as_uint(v);
    unsigned r = u + 0x7fffu + ((u >> 16) & 1u);
    return (unsigned short)(r >> 16);
}
__device__ __forceinline__ float bf2f(unsigned short s) {
    return __uint_as_float(((unsigned)s) << 16);
}

// ---------------- bucket cursor init: bcur[b] = b*cap ----------------
__global__ void k_binit(int* __restrict__ bcur, int NB, int cap) {
    int b = blockIdx.x * 256 + threadIdx.x;
    if (b < NB) bcur[b] = b * cap;
}

// ---------------- pass 1: bin edges by dst>>8 into bucket regions ----------
// packed entry: src | (dst&255)<<24   (requires N < 2^24)
__global__ __launch_bounds__(256) void k_bin(const int* __restrict__ src,
                                             const int* __restrict__ dst,
                                             int* __restrict__ bcur,
                                             int* __restrict__ binned, int E, int NB) {
    __shared__ int histA[NBMAX], histB[NBMAX], gbase[NBMAX];
    int tid = threadIdx.x;
    int e0 = blockIdx.x * BTILE;
    for (int b = tid; b < NB; b += 256) { histA[b] = 0; histB[b] = 0; }
    __syncthreads();
    #pragma unroll
    for (int u = 0; u < BTILE / 256; ++u) {
        int i = e0 + u * 256 + tid;
        if (i < E) atomicAdd(&histA[dst[i] >> 8], 1);
    }
    __syncthreads();
    for (int b = tid; b < NB; b += 256) {
        int c = histA[b];
        gbase[b] = c ? atomicAdd(&bcur[b], c) : 0;
    }
    __syncthreads();
    #pragma unroll
    for (int u = 0; u < BTILE / 256; ++u) {
        int i = e0 + u * 256 + tid;
        if (i < E) {
            int d = dst[i];
            int b = d >> 8;
            int r = atomicAdd(&histB[b], 1);
            binned[gbase[b] + r] = src[i] | ((d & 255) << 24);
        }
    }
}

// ---------------- bucket-base scan: single block over NB<=512 totals ----------
__global__ void k_scanb(const int* __restrict__ bcur, int* __restrict__ bbase,
                        int NB, int cap) {
    __shared__ int s[512];
    int t = threadIdx.x;
    int v = (t < NB) ? (bcur[t] - t * cap) : 0;
    s[t] = v;
    __syncthreads();
    for (int off = 1; off < 512; off <<= 1) {
        int add = (t >= off) ? s[t - off] : 0;
        __syncthreads();
        s[t] += add;
        __syncthreads();
    }
    bbase[t] = s[t] - v;   // exclusive bucket base
}

// ---------------- pass 2a: per-bucket degree count + local scan -> rowptr/dinv --
__global__ __launch_bounds__(256) void k_bcount2(const int* __restrict__ binned,
                                                 const int* __restrict__ bcur,
                                                 const int* __restrict__ bbase,
                                                 int* __restrict__ cnt_tot,
                                                 int* __restrict__ rowptr_tot,
                                                 float* __restrict__ dinv,
                                                 int cap, int N) {
    __shared__ int h[256], sc[256];
    int b = blockIdx.x;
    int tid = threadIdx.x;
    h[tid] = 0;
    __syncthreads();
    int base = b * cap;
    int ne = bcur[b] - base;
    for (int i = tid; i < ne; i += 256)
        atomicAdd(&h[(binned[base + i] >> 24) & 255], 1);
    __syncthreads();
    int c = h[tid];
    sc[tid] = c;
    __syncthreads();
    for (int off = 1; off < 256; off <<= 1) {
        int add = (tid >= off) ? sc[tid - off] : 0;
        __syncthreads();
        sc[tid] += add;
        __syncthreads();
    }
    int v = (b << 8) + tid;
    if (v < N) {
        cnt_tot[v] = c;
        rowptr_tot[v] = bbase[b] + sc[tid] - c;   // exclusive, bucket-major
        dinv[v] = rsqrtf((float)(c + 1));
    }
}

// ---------------- pass 2b: per-bucket scatter + wsrc (LDS cursors) ------------
__global__ __launch_bounds__(256) void k_scatter(const int* __restrict__ binned,
                                                 const int* __restrict__ bcur,
                                                 const int* __restrict__ rowptr_tot,
                                                 const float* __restrict__ dinv,
                                                 int* __restrict__ esrc,
                                                 float* __restrict__ wsrc, int cap, int N) {
    __shared__ int cur[256];
    int b = blockIdx.x;
    int tid = threadIdx.x;
    int node0 = b << 8;
    int v = node0 + tid;
    cur[tid] = (v < N) ? rowptr_tot[v] : 0;
    __syncthreads();
    int base = b * cap;
    int ne = bcur[b] - base;
    for (int i = tid; i < ne; i += 256) {
        int pk = binned[base + i];
        int pos = atomicAdd(&cur[(pk >> 24) & 255], 1);
        esrc[pos] = pk & 0x00FFFFFF;
    }
    __syncthreads();
    int r0 = rowptr_tot[node0];
    for (int i = r0 + tid; i < r0 + ne; i += 256) wsrc[i] = dinv[esrc[i]];
}

// ---------------- GEMM1 (MFMA bf16 hi/lo split): h1(fp16) = x @ W1 -------------
__global__ __launch_bounds__(256) void k_gemm1(const float* __restrict__ x,
                                               const float* __restrict__ W1,
                                               __half* __restrict__ h1, int n) {
    __shared__ __align__(16) unsigned short Ah[2048], Al[2048], Bh[2048], Bl[2048];
    int tid = threadIdx.x;
    int lane = tid & 63;
    int wid = tid >> 6;          // rowgroup 0..3
    int m0 = blockIdx.x * 64;
    f32x4 acc[4] = {{0.f, 0.f, 0.f, 0.f}, {0.f, 0.f, 0.f, 0.f},
                    {0.f, 0.f, 0.f, 0.f}, {0.f, 0.f, 0.f, 0.f}};

    int bcol = tid & 63;
    int bkq = tid >> 6;          // k-quad 0..3
    int bIdx = ((bcol >> 4) * 512) + (((bkq << 4) | (bcol & 15)) * 8);  // shorts

    for (int k0 = 0; k0 < NF; k0 += 32) {
        #pragma unroll
        for (int it = 0; it < 2; ++it) {
            int f = tid + it * 256;
            int m = f >> 3;
            int g = f & 7;
            int node = m0 + m;
            float4 xv = make_float4(0.f, 0.f, 0.f, 0.f);
            if (node < n) xv = *(const float4*)&x[(size_t)node * NF + k0 + g * 4];
            ushort4 hi, lo;
            hi.x = f2bf(xv.x); lo.x = f2bf(xv.x - bf2f(hi.x));
            hi.y = f2bf(xv.y); lo.y = f2bf(xv.y - bf2f(hi.y));
            hi.z = f2bf(xv.z); lo.z = f2bf(xv.z - bf2f(hi.z));
            hi.w = f2bf(xv.w); lo.w = f2bf(xv.w - bf2f(hi.w));
            int aIdx = ((m >> 4) * 512) + ((((g >> 1) << 4) | (m & 15)) * 8) + (g & 1) * 4;
            *(ushort4*)&Ah[aIdx] = hi;
            *(ushort4*)&Al[aIdx] = lo;
        }
        {
            unsigned short hb[8], lb[8];
            #pragma unroll
            for (int j = 0; j < 8; ++j) {
                float w = W1[(size_t)(k0 + bkq * 8 + j) * NH + bcol];
                hb[j] = f2bf(w);
                lb[j] = f2bf(w - bf2f(hb[j]));
            }
            #pragma unroll
            for (int j = 0; j < 8; ++j) { Bh[bIdx + j] = hb[j]; Bl[bIdx + j] = lb[j]; }
        }
        __syncthreads();
        bf16x8 ah = __builtin_bit_cast(bf16x8, *(short8*)&Ah[wid * 512 + lane * 8]);
        bf16x8 al = __builtin_bit_cast(bf16x8, *(short8*)&Al[wid * 512 + lane * 8]);
        #pragma unroll
        for (int c = 0; c < 4; ++c) {
            bf16x8 bh = __builtin_bit_cast(bf16x8, *(short8*)&Bh[c * 512 + lane * 8]);
            bf16x8 bl = __builtin_bit_cast(bf16x8, *(short8*)&Bl[c * 512 + lane * 8]);
            acc[c] = __builtin_amdgcn_mfma_f32_16x16x32_bf16(ah, bh, acc[c], 0, 0, 0);
            acc[c] = __builtin_amdgcn_mfma_f32_16x16x32_bf16(al, bh, acc[c], 0, 0, 0);
            acc[c] = __builtin_amdgcn_mfma_f32_16x16x32_bf16(ah, bl, acc[c], 0, 0, 0);
        }
        __syncthreads();
    }
    int quad = lane >> 4;
    int cl = lane & 15;
    #pragma unroll
    for (int c = 0; c < 4; ++c) {
        #pragma unroll
        for (int r = 0; r < 4; ++r) {
            int row = m0 + wid * 16 + quad * 4 + r;
            if (row < n) h1[(size_t)row * NH + c * 16 + cl] = __float2half_rn(acc[c][r]);
        }
    }
}

// ---------------- agg1 + bias + relu + FUSED GEMM2 -> g(fp16) ------------------
// Wave per node (grid-stride). Lane layout: es = lane>>3 (edge slot 0..7, also
// class-pair index), fl = lane&7 (features [8*fl, 8*fl+8)).
// Gather: dwordx4 = 8 halves/lane -> 8 full rows (1 KB) per wave-instruction.
// All shuffles convergent: trip counts (rem, nbp) are wave-uniform; padded
// lanes carry s=v (valid row) and w=0.
__global__ __launch_bounds__(256) void k_agg1f(const __half* __restrict__ h1,
                                               const float* __restrict__ dinv,
                                               const int* __restrict__ rowptr_tot,
                                               const int* __restrict__ cnt_tot,
                                               const int* __restrict__ esrc,
                                               const float* __restrict__ wsrc,
                                               const float* __restrict__ b1,
                                               const float* __restrict__ W2,
                                               __half2* __restrict__ g, int n) {
    int lane = threadIdx.x & 63;
    int wid = threadIdx.x >> 6;
    int es = lane >> 3;
    int fl = lane & 7;
    // register-resident W2 slice: classes (2*es, 2*es+1) x features (8*fl+k)
    float2 w2[8];
    #pragma unroll
    for (int k = 0; k < 8; ++k)
        w2[k] = *(const float2*)&W2[(size_t)(8 * fl + k) * NC + 2 * es];
    float b1r[8];
    #pragma unroll
    for (int k = 0; k < 8; ++k) b1r[k] = b1[8 * fl + k];

    int stride = gridDim.x * 4;
    for (int v = blockIdx.x * 4 + wid; v < n; v += stride) {
        float dv = dinv[v];
        float acc[8] = {0.f, 0.f, 0.f, 0.f, 0.f, 0.f, 0.f, 0.f};
        {   // self-loop: weight only on edge-slot 0 (others add 0, same row)
            float ww = (es == 0) ? dv * dv : 0.f;
            uint4 pk = *(const uint4*)&h1[(size_t)v * NH + 8 * fl];
            const __half2* ph = (const __half2*)&pk;
            #pragma unroll
            for (int q = 0; q < 4; ++q) {
                float2 f = __half22float2(ph[q]);
                acc[2 * q]     = fmaf(ww, f.x, acc[2 * q]);
                acc[2 * q + 1] = fmaf(ww, f.y, acc[2 * q + 1]);
            }
        }
        int beg = rowptr_tot[v];
        int ecnt = cnt_tot[v];
        for (int base = 0; base < ecnt; base += 64) {
            int rem = ecnt - base;
            if (rem > 64) rem = 64;
            int s = v;
            float w = 0.f;
            if (lane < rem) {
                s = esrc[beg + base + lane];
                w = wsrc[beg + base + lane] * dv;
            }
            int nbp = (rem + 15) >> 4;   // pairs of 8 edges: 2-deep gather ILP
            for (int t = 0; t < nbp; ++t) {
                int e0 = t * 16 + es;
                int e1 = e0 + 8;
                int sj0 = __shfl(s, e0);
                float w0 = __shfl(w, e0);
                int sj1 = __shfl(s, e1);
                float w1 = __shfl(w, e1);
                uint4 pk0 = *(const uint4*)&h1[(size_t)sj0 * NH + 8 * fl];
                uint4 pk1 = *(const uint4*)&h1[(size_t)sj1 * NH + 8 * fl];
                const __half2* p0 = (const __half2*)&pk0;
                const __half2* p1 = (const __half2*)&pk1;
                #pragma unroll
                for (int q = 0; q < 4; ++q) {
                    float2 f0 = __half22float2(p0[q]);
                    float2 f1 = __half22float2(p1[q]);
                    acc[2 * q]     = fmaf(w0, f0.x, acc[2 * q]);
                    acc[2 * q + 1] = fmaf(w0, f0.y, acc[2 * q + 1]);
                    acc[2 * q]     = fmaf(w1, f1.x, acc[2 * q]);
                    acc[2 * q + 1] = fmaf(w1, f1.y, acc[2 * q + 1]);
                }
            }
        }
        // reduce partials across the 8 edge-slots (xor 8,16,32)
        #pragma unroll
        for (int m = 8; m < 64; m <<= 1) {
            #pragma unroll
            for (int k = 0; k < 8; ++k) acc[k] += __shfl_xor(acc[k], m);
        }
        // bias + relu
        float h[8];
        #pragma unroll
        for (int k = 0; k < 8; ++k) h[k] = fmaxf(acc[k] + b1r[k], 0.f);
        // fused GEMM2: partial over this lane's 8 features, 2 classes
        float p0 = 0.f, p1 = 0.f;
        #pragma unroll
        for (int k = 0; k < 8; ++k) {
            p0 = fmaf(h[k], w2[k].x, p0);
            p1 = fmaf(h[k], w2[k].y, p1);
        }
        #pragma unroll
        for (int m = 1; m < 8; m <<= 1) {   // reduce over fl (xor 1,2,4)
            p0 += __shfl_xor(p0, m);
            p1 += __shfl_xor(p1, m);
        }
        if (fl == 0) g[(size_t)v * 8 + es] = __floats2half2_rn(p0, p1);
    }
}

// ---------------- agg2 + bias + log_softmax: 8-lane group/node, half2 ----------
// g table fp16 (3.2 MB, L2-resident). Lane cl owns class pair (2cl, 2cl+1).
// Padded gathers re-read the batch's first row (same address -> cache hit).
__global__ __launch_bounds__(256) void k_agg2v(const __half2* __restrict__ g,
                                               const float* __restrict__ dinv,
                                               const int* __restrict__ rowptr_tot,
                                               const int* __restrict__ cnt_tot,
                                               const int* __restrict__ esrc,
                                               const float* __restrict__ wsrc,
                                               const float* __restrict__ b2,
                                               float* __restrict__ out, int n) {
    int v = blockIdx.x * 32 + (threadIdx.x >> 3);
    int cl = threadIdx.x & 7;
    if (v >= n) return;
    float dv = dinv[v];
    float2 a;
    {
        float2 f = __half22float2(g[(size_t)v * 8 + cl]);
        float sw = dv * dv;
        a.x = sw * f.x;
        a.y = sw * f.y;
    }
    int beg = rowptr_tot[v];
    int end = beg + cnt_tot[v];
    for (int base = beg; base < end; base += 8) {
        int c = end - base;
        if (c > 8) c = 8;
        int s = 0;
        float w = 0.f;
        if (cl < c) {
            s = esrc[base + cl];
            w = wsrc[base + cl] * dv;
        }
        #pragma unroll
        for (int u = 0; u < 8; ++u) {
            int pick = (u < c) ? u : 0;
            int sj = __shfl(s, pick, 8);
            float wv = __shfl(w, pick, 8);
            float ww = (u < c) ? wv : 0.f;
            float2 f = __half22float2(g[(size_t)sj * 8 + cl]);
            a.x = fmaf(ww, f.x, a.x);
            a.y = fmaf(ww, f.y, a.y);
        }
    }
    a.x += b2[2 * cl];
    a.y += b2[2 * cl + 1];
    float m = fmaxf(a.x, a.y);
    #pragma unroll
    for (int mask = 1; mask < 8; mask <<= 1) m = fmaxf(m, __shfl_xor(m, mask, 8));
    float ex = __expf(a.x - m) + __expf(a.y - m);
    #pragma unroll
    for (int mask = 1; mask < 8; mask <<= 1) ex += __shfl_xor(ex, mask, 8);
    float ls = m + __logf(ex);
    *(float2*)&out[(size_t)v * NC + 2 * cl] = make_float2(a.x - ls, a.y - ls);
}

extern "C" void kernel_launch(void* const* d_in, const int* in_sizes, int n_in,
                              void* d_out, int out_size, void* d_ws, size_t ws_size,
                              hipStream_t stream) {
    const float* x  = (const float*)d_in[0];
    const int*   ei = (const int*)d_in[1];
    const float* W1 = (const float*)d_in[2];
    const float* b1 = (const float*)d_in[3];
    const float* W2 = (const float*)d_in[4];
    const float* b2 = (const float*)d_in[5];
    float* out = (float*)d_out;

    const int N = in_sizes[0] / NF;
    const int E = in_sizes[1] / 2;
    const int* src = ei;
    const int* dst = ei + E;

    const int NB  = (N + 255) >> 8;                       // buckets of 256 nodes
    const int per = (E + NB - 1) / NB;
    const int cap = (per + (per >> 2) + 511) & ~511;      // +25% slack, 512-aligned

    // workspace layout (64B-aligned slices; no aliasing — agg1f reads h1 while
    // writing g, and binned must survive through k_scatter)
    char* ws = (char*)d_ws;
    size_t o = 0;
    auto alloc = [&](size_t bytes) {
        o = (o + 63) & ~(size_t)63;
        void* p = ws + o;
        o += bytes;
        return p;
    };
    int*    cnt_tot    = (int*)alloc((size_t)N * 4);
    int*    rowptr_tot = (int*)alloc((size_t)N * 4);
    float*  dinv       = (float*)alloc((size_t)N * 4);
    int*    bcur       = (int*)alloc((size_t)NBMAX * 4);
    int*    bbase      = (int*)alloc((size_t)NBMAX * 4);
    int*    esrc       = (int*)alloc((size_t)E * 4);            // 6.4 MB
    float*  wsrc       = (float*)alloc((size_t)E * 4);          // 6.4 MB
    __half* h1         = (__half*)alloc((size_t)N * NH * 2);    // 12.8 MB fp16
    __half2* g         = (__half2*)alloc((size_t)N * NC * 2);   // 3.2 MB fp16
    int*    binned     = (int*)alloc((size_t)NB * cap * 4);     // ~8 MB

    int nbin = (E + BTILE - 1) / BTILE;

    k_binit<<<(NB + 255) / 256, 256, 0, stream>>>(bcur, NB, cap);
    k_bin<<<nbin, 256, 0, stream>>>(src, dst, bcur, binned, E, NB);
    k_scanb<<<1, 512, 0, stream>>>(bcur, bbase, NB, cap);
    k_bcount2<<<NB, 256, 0, stream>>>(binned, bcur, bbase, cnt_tot, rowptr_tot, dinv, cap, N);
    k_scatter<<<NB, 256, 0, stream>>>(binned, bcur, rowptr_tot, dinv, esrc, wsrc, cap, N);

    k_gemm1<<<(N + 63) / 64, 256, 0, stream>>>(x, W1, h1, N);
    k_agg1f<<<2048, 256, 0, stream>>>(h1, dinv, rowptr_tot, cnt_tot, esrc, wsrc, b1, W2, g, N);
    k_agg2v<<<(N + 31) / 32, 256, 0, stream>>>(g, dinv, rowptr_tot, cnt_tot, esrc, wsrc, b2, out, N);
}

// Round 2
// 312.815 us; speedup vs baseline: 1.0850x; 1.0696x over previous
//
#include <hip/hip_runtime.h>
#include <hip/hip_bf16.h>
#include <hip/hip_fp16.h>
#include <math.h>

#define NF 256
#define NH 64
#define NC 16
#define NBMAX 512      // max buckets (N/256 <= 512 -> N <= 131072)
#define BTILE 4096     // edges per k_bin block
#define PCAP 6144      // LDS staging capacity in k_prep (bucket edges ~4096+-64)

typedef __attribute__((ext_vector_type(8))) __bf16 bf16x8;
typedef __attribute__((ext_vector_type(4))) float f32x4;
typedef __attribute__((ext_vector_type(8))) short short8;

__device__ __forceinline__ unsigned short f2bf(float v) {   // RNE fp32->bf16
    unsigned u = __float_as_uint(v);
    unsigned r = u + 0x7fffu + ((u >> 16) & 1u);
    return (unsigned short)(r >> 16);
}
__device__ __forceinline__ float bf2f(unsigned short s) {
    return __uint_as_float(((unsigned)s) << 16);
}

// ---------------- bucket cursor init: bcur[b] = b*cap ----------------
__global__ void k_binit(int* __restrict__ bcur, int NB, int cap) {
    int b = blockIdx.x * 256 + threadIdx.x;
    if (b < NB) bcur[b] = b * cap;
}

// ---------------- pass 1: bin edges by dst>>8 into bucket regions ----------
// packed entry: src | (dst&255)<<24   (requires N < 2^24)
__global__ __launch_bounds__(256) void k_bin(const int* __restrict__ src,
                                             const int* __restrict__ dst,
                                             int* __restrict__ bcur,
                                             int* __restrict__ binned, int E, int NB) {
    __shared__ int histA[NBMAX], histB[NBMAX], gbase[NBMAX];
    int tid = threadIdx.x;
    int e0 = blockIdx.x * BTILE;
    for (int b = tid; b < NB; b += 256) { histA[b] = 0; histB[b] = 0; }
    __syncthreads();
    #pragma unroll
    for (int u = 0; u < BTILE / 256; ++u) {
        int i = e0 + u * 256 + tid;
        if (i < E) atomicAdd(&histA[dst[i] >> 8], 1);
    }
    __syncthreads();
    for (int b = tid; b < NB; b += 256) {
        int c = histA[b];
        gbase[b] = c ? atomicAdd(&bcur[b], c) : 0;
    }
    __syncthreads();
    #pragma unroll
    for (int u = 0; u < BTILE / 256; ++u) {
        int i = e0 + u * 256 + tid;
        if (i < E) {
            int d = dst[i];
            int b = d >> 8;
            int r = atomicAdd(&histB[b], 1);
            binned[gbase[b] + r] = src[i] | ((d & 255) << 24);
        }
    }
}

// ---------------- bucket-base scan: single block over NB<=512 totals ----------
__global__ void k_scanb(const int* __restrict__ bcur, int* __restrict__ bbase,
                        int NB, int cap) {
    __shared__ int s[512];
    int t = threadIdx.x;
    int v = (t < NB) ? (bcur[t] - t * cap) : 0;
    s[t] = v;
    __syncthreads();
    for (int off = 1; off < 512; off <<= 1) {
        int add = (t >= off) ? s[t - off] : 0;
        __syncthreads();
        s[t] += add;
        __syncthreads();
    }
    bbase[t] = s[t] - v;   // exclusive bucket base
}

// ---------------- fused prep: stage bucket in LDS, hist+scan -> cnt/rowptr/dinv,
// then scatter esrc. Reads binned ONCE. No wsrc (w recomputed from dinv in aggs).
__global__ __launch_bounds__(256) void k_prep(const int* __restrict__ binned,
                                              const int* __restrict__ bcur,
                                              const int* __restrict__ bbase,
                                              int* __restrict__ cnt_tot,
                                              int* __restrict__ rowptr_tot,
                                              float* __restrict__ dinv,
                                              int* __restrict__ esrc,
                                              int cap, int N) {
    __shared__ int eb[PCAP];
    __shared__ int h[256], sc[256];
    int b = blockIdx.x;
    int tid = threadIdx.x;
    int base = b * cap;
    int ne = bcur[b] - base;
    if (ne > PCAP) ne = PCAP;   // safety (never hit at this E/N; ~4096+-5*64)
    h[tid] = 0;
    for (int i = tid; i < ne; i += 256) eb[i] = binned[base + i];
    __syncthreads();
    for (int i = tid; i < ne; i += 256) atomicAdd(&h[(eb[i] >> 24) & 255], 1);
    __syncthreads();
    int c = h[tid];
    sc[tid] = c;
    __syncthreads();
    for (int off = 1; off < 256; off <<= 1) {
        int add = (tid >= off) ? sc[tid - off] : 0;
        __syncthreads();
        sc[tid] += add;
        __syncthreads();
    }
    int rp = bbase[b] + sc[tid] - c;      // exclusive, bucket-major
    int v = (b << 8) + tid;
    if (v < N) {
        cnt_tot[v] = c;
        rowptr_tot[v] = rp;
        dinv[v] = rsqrtf((float)(c + 1));
    }
    sc[tid] = rp;                         // reuse as scatter cursor
    __syncthreads();
    for (int i = tid; i < ne; i += 256) {
        int pk = eb[i];
        int pos = atomicAdd(&sc[(pk >> 24) & 255], 1);
        esrc[pos] = pk & 0x00FFFFFF;
    }
}

// ---------------- GEMM1 (MFMA bf16 hi/lo split): h1(fp16) = x @ W1 -------------
__global__ __launch_bounds__(256) void k_gemm1(const float* __restrict__ x,
                                               const float* __restrict__ W1,
                                               __half* __restrict__ h1, int n) {
    __shared__ __align__(16) unsigned short Ah[2048], Al[2048], Bh[2048], Bl[2048];
    int tid = threadIdx.x;
    int lane = tid & 63;
    int wid = tid >> 6;          // rowgroup 0..3
    int m0 = blockIdx.x * 64;
    f32x4 acc[4] = {{0.f, 0.f, 0.f, 0.f}, {0.f, 0.f, 0.f, 0.f},
                    {0.f, 0.f, 0.f, 0.f}, {0.f, 0.f, 0.f, 0.f}};

    int bcol = tid & 63;
    int bkq = tid >> 6;          // k-quad 0..3
    int bIdx = ((bcol >> 4) * 512) + (((bkq << 4) | (bcol & 15)) * 8);  // shorts

    for (int k0 = 0; k0 < NF; k0 += 32) {
        #pragma unroll
        for (int it = 0; it < 2; ++it) {
            int f = tid + it * 256;
            int m = f >> 3;
            int g = f & 7;
            int node = m0 + m;
            float4 xv = make_float4(0.f, 0.f, 0.f, 0.f);
            if (node < n) xv = *(const float4*)&x[(size_t)node * NF + k0 + g * 4];
            ushort4 hi, lo;
            hi.x = f2bf(xv.x); lo.x = f2bf(xv.x - bf2f(hi.x));
            hi.y = f2bf(xv.y); lo.y = f2bf(xv.y - bf2f(hi.y));
            hi.z = f2bf(xv.z); lo.z = f2bf(xv.z - bf2f(hi.z));
            hi.w = f2bf(xv.w); lo.w = f2bf(xv.w - bf2f(hi.w));
            int aIdx = ((m >> 4) * 512) + ((((g >> 1) << 4) | (m & 15)) * 8) + (g & 1) * 4;
            *(ushort4*)&Ah[aIdx] = hi;
            *(ushort4*)&Al[aIdx] = lo;
        }
        {
            unsigned short hb[8], lb[8];
            #pragma unroll
            for (int j = 0; j < 8; ++j) {
                float w = W1[(size_t)(k0 + bkq * 8 + j) * NH + bcol];
                hb[j] = f2bf(w);
                lb[j] = f2bf(w - bf2f(hb[j]));
            }
            #pragma unroll
            for (int j = 0; j < 8; ++j) { Bh[bIdx + j] = hb[j]; Bl[bIdx + j] = lb[j]; }
        }
        __syncthreads();
        bf16x8 ah = __builtin_bit_cast(bf16x8, *(short8*)&Ah[wid * 512 + lane * 8]);
        bf16x8 al = __builtin_bit_cast(bf16x8, *(short8*)&Al[wid * 512 + lane * 8]);
        #pragma unroll
        for (int c = 0; c < 4; ++c) {
            bf16x8 bh = __builtin_bit_cast(bf16x8, *(short8*)&Bh[c * 512 + lane * 8]);
            bf16x8 bl = __builtin_bit_cast(bf16x8, *(short8*)&Bl[c * 512 + lane * 8]);
            acc[c] = __builtin_amdgcn_mfma_f32_16x16x32_bf16(ah, bh, acc[c], 0, 0, 0);
            acc[c] = __builtin_amdgcn_mfma_f32_16x16x32_bf16(al, bh, acc[c], 0, 0, 0);
            acc[c] = __builtin_amdgcn_mfma_f32_16x16x32_bf16(ah, bl, acc[c], 0, 0, 0);
        }
        __syncthreads();
    }
    int quad = lane >> 4;
    int cl = lane & 15;
    #pragma unroll
    for (int c = 0; c < 4; ++c) {
        #pragma unroll
        for (int r = 0; r < 4; ++r) {
            int row = m0 + wid * 16 + quad * 4 + r;
            if (row < n) h1[(size_t)row * NH + c * 16 + cl] = __float2half_rn(acc[c][r]);
        }
    }
}

// ---------------- agg1 + bias + relu + FUSED GEMM2 -> g(fp16), DUAL-NODE -------
// Wave processes node pair (2p, 2p+1) concurrently: 4 gathers in flight (vs 2),
// reduction tails interleave (ILP-2). es = lane>>3 (edge slot / class pair),
// fl = lane&7 (features [8fl,8fl+8)). Weight recomputed as dinv[s]*dinv[v]
// (dinv = 400 KB, L2-resident). All shuffles convergent: trip counts derive
// from wave-uniform r0/r1; padded lanes carry s=v0 (valid row) and w=0.
__global__ __launch_bounds__(256) void k_agg1f(const __half* __restrict__ h1,
                                               const float* __restrict__ dinv,
                                               const int* __restrict__ rowptr_tot,
                                               const int* __restrict__ cnt_tot,
                                               const int* __restrict__ esrc,
                                               const float* __restrict__ b1,
                                               const float* __restrict__ W2,
                                               __half2* __restrict__ g, int n) {
    int lane = threadIdx.x & 63;
    int wid = threadIdx.x >> 6;
    int es = lane >> 3;
    int fl = lane & 7;
    float2 w2[8];
    float b1r[8];
    #pragma unroll
    for (int k = 0; k < 8; ++k) {
        w2[k] = *(const float2*)&W2[(size_t)(8 * fl + k) * NC + 2 * es];
        b1r[k] = b1[8 * fl + k];
    }
    int pairs = (n + 1) >> 1;
    int stride = gridDim.x * 4;
    for (int p = blockIdx.x * 4 + wid; p < pairs; p += stride) {
        int v0 = 2 * p;
        int v1 = v0 + 1;
        bool val1 = v1 < n;
        float dv0 = dinv[v0];
        float dv1 = val1 ? dinv[v1] : 0.f;
        int beg0 = rowptr_tot[v0], c0 = cnt_tot[v0];
        int beg1 = val1 ? rowptr_tot[v1] : 0;
        int c1 = val1 ? cnt_tot[v1] : 0;
        float a0[8] = {0.f, 0.f, 0.f, 0.f, 0.f, 0.f, 0.f, 0.f};
        float a1[8] = {0.f, 0.f, 0.f, 0.f, 0.f, 0.f, 0.f, 0.f};
        {   // self-loops (weight only on es==0; other slots add 0 of same row)
            float sw0 = (es == 0) ? dv0 * dv0 : 0.f;
            float sw1 = (es == 0) ? dv1 * dv1 : 0.f;
            uint4 q0 = *(const uint4*)&h1[(size_t)v0 * NH + 8 * fl];
            uint4 q1 = *(const uint4*)&h1[(size_t)(val1 ? v1 : v0) * NH + 8 * fl];
            const __half2* ph0 = (const __half2*)&q0;
            const __half2* ph1 = (const __half2*)&q1;
            #pragma unroll
            for (int q = 0; q < 4; ++q) {
                float2 f0 = __half22float2(ph0[q]);
                float2 f1 = __half22float2(ph1[q]);
                a0[2 * q]     = fmaf(sw0, f0.x, a0[2 * q]);
                a0[2 * q + 1] = fmaf(sw0, f0.y, a0[2 * q + 1]);
                a1[2 * q]     = fmaf(sw1, f1.x, a1[2 * q]);
                a1[2 * q + 1] = fmaf(sw1, f1.y, a1[2 * q + 1]);
            }
        }
        int cmax = c0 > c1 ? c0 : c1;
        for (int base = 0; base < cmax; base += 64) {
            int r0 = c0 - base; if (r0 > 64) r0 = 64;
            int r1 = c1 - base; if (r1 > 64) r1 = 64;
            int s0 = v0; float w0 = 0.f;
            int s1 = v0; float w1 = 0.f;
            if (lane < r0) { s0 = esrc[beg0 + base + lane]; w0 = dinv[s0] * dv0; }
            if (lane < r1) { s1 = esrc[beg1 + base + lane]; w1 = dinv[s1] * dv1; }
            int rmax = r0 > r1 ? r0 : r1;
            int nbp = (rmax + 15) >> 4;
            for (int t = 0; t < nbp; ++t) {
                int e0 = t * 16 + es;
                int e1 = e0 + 8;
                int sj00 = __shfl(s0, e0); float w00 = __shfl(w0, e0);
                int sj01 = __shfl(s0, e1); float w01 = __shfl(w0, e1);
                int sj10 = __shfl(s1, e0); float w10 = __shfl(w1, e0);
                int sj11 = __shfl(s1, e1); float w11 = __shfl(w1, e1);
                uint4 pk00 = *(const uint4*)&h1[(size_t)sj00 * NH + 8 * fl];
                uint4 pk01 = *(const uint4*)&h1[(size_t)sj01 * NH + 8 * fl];
                uint4 pk10 = *(const uint4*)&h1[(size_t)sj10 * NH + 8 * fl];
                uint4 pk11 = *(const uint4*)&h1[(size_t)sj11 * NH + 8 * fl];
                const __half2* p00 = (const __half2*)&pk00;
                const __half2* p01 = (const __half2*)&pk01;
                const __half2* p10 = (const __half2*)&pk10;
                const __half2* p11 = (const __half2*)&pk11;
                #pragma unroll
                for (int q = 0; q < 4; ++q) {
                    float2 f00 = __half22float2(p00[q]);
                    float2 f01 = __half22float2(p01[q]);
                    a0[2 * q]     = fmaf(w00, f00.x, a0[2 * q]);
                    a0[2 * q + 1] = fmaf(w00, f00.y, a0[2 * q + 1]);
                    a0[2 * q]     = fmaf(w01, f01.x, a0[2 * q]);
                    a0[2 * q + 1] = fmaf(w01, f01.y, a0[2 * q + 1]);
                    float2 f10 = __half22float2(p10[q]);
                    float2 f11 = __half22float2(p11[q]);
                    a1[2 * q]     = fmaf(w10, f10.x, a1[2 * q]);
                    a1[2 * q + 1] = fmaf(w10, f10.y, a1[2 * q + 1]);
                    a1[2 * q]     = fmaf(w11, f11.x, a1[2 * q]);
                    a1[2 * q + 1] = fmaf(w11, f11.y, a1[2 * q + 1]);
                }
            }
        }
        // reduce partials across the 8 edge-slots (xor 8,16,32) — ILP-2
        #pragma unroll
        for (int m = 8; m < 64; m <<= 1) {
            #pragma unroll
            for (int k = 0; k < 8; ++k) {
                a0[k] += __shfl_xor(a0[k], m);
                a1[k] += __shfl_xor(a1[k], m);
            }
        }
        // bias + relu + fused GEMM2 partials (2 classes per lane, both nodes)
        float p00 = 0.f, p01 = 0.f, p10 = 0.f, p11 = 0.f;
        #pragma unroll
        for (int k = 0; k < 8; ++k) {
            float h0 = fmaxf(a0[k] + b1r[k], 0.f);
            float h1v = fmaxf(a1[k] + b1r[k], 0.f);
            p00 = fmaf(h0, w2[k].x, p00);
            p01 = fmaf(h0, w2[k].y, p01);
            p10 = fmaf(h1v, w2[k].x, p10);
            p11 = fmaf(h1v, w2[k].y, p11);
        }
        #pragma unroll
        for (int m = 1; m < 8; m <<= 1) {   // reduce over fl (xor 1,2,4)
            p00 += __shfl_xor(p00, m);
            p01 += __shfl_xor(p01, m);
            p10 += __shfl_xor(p10, m);
            p11 += __shfl_xor(p11, m);
        }
        if (fl == 0) {
            g[(size_t)v0 * 8 + es] = __floats2half2_rn(p00, p01);
            if (val1) g[(size_t)v1 * 8 + es] = __floats2half2_rn(p10, p11);
        }
    }
}

// ---------------- agg2 + bias + log_softmax: 8-lane group/node, half2 ----------
// g table fp16 (3.2 MB, L2-resident). Lane cl owns class pair (2cl, 2cl+1).
// Weight from L2-resident dinv gather (wsrc eliminated).
__global__ __launch_bounds__(256) void k_agg2v(const __half2* __restrict__ g,
                                               const float* __restrict__ dinv,
                                               const int* __restrict__ rowptr_tot,
                                               const int* __restrict__ cnt_tot,
                                               const int* __restrict__ esrc,
                                               const float* __restrict__ b2,
                                               float* __restrict__ out, int n) {
    int v = blockIdx.x * 32 + (threadIdx.x >> 3);
    int cl = threadIdx.x & 7;
    if (v >= n) return;
    float dv = dinv[v];
    float2 a;
    {
        float2 f = __half22float2(g[(size_t)v * 8 + cl]);
        float sw = dv * dv;
        a.x = sw * f.x;
        a.y = sw * f.y;
    }
    int beg = rowptr_tot[v];
    int end = beg + cnt_tot[v];
    for (int base = beg; base < end; base += 8) {
        int c = end - base;
        if (c > 8) c = 8;
        int s = 0;
        float w = 0.f;
        if (cl < c) {
            s = esrc[base + cl];
            w = dinv[s] * dv;
        }
        #pragma unroll
        for (int u = 0; u < 8; ++u) {
            int pick = (u < c) ? u : 0;
            int sj = __shfl(s, pick, 8);
            float wv = __shfl(w, pick, 8);
            float ww = (u < c) ? wv : 0.f;
            float2 f = __half22float2(g[(size_t)sj * 8 + cl]);
            a.x = fmaf(ww, f.x, a.x);
            a.y = fmaf(ww, f.y, a.y);
        }
    }
    a.x += b2[2 * cl];
    a.y += b2[2 * cl + 1];
    float m = fmaxf(a.x, a.y);
    #pragma unroll
    for (int mask = 1; mask < 8; mask <<= 1) m = fmaxf(m, __shfl_xor(m, mask, 8));
    float ex = __expf(a.x - m) + __expf(a.y - m);
    #pragma unroll
    for (int mask = 1; mask < 8; mask <<= 1) ex += __shfl_xor(ex, mask, 8);
    float ls = m + __logf(ex);
    *(float2*)&out[(size_t)v * NC + 2 * cl] = make_float2(a.x - ls, a.y - ls);
}

extern "C" void kernel_launch(void* const* d_in, const int* in_sizes, int n_in,
                              void* d_out, int out_size, void* d_ws, size_t ws_size,
                              hipStream_t stream) {
    const float* x  = (const float*)d_in[0];
    const int*   ei = (const int*)d_in[1];
    const float* W1 = (const float*)d_in[2];
    const float* b1 = (const float*)d_in[3];
    const float* W2 = (const float*)d_in[4];
    const float* b2 = (const float*)d_in[5];
    float* out = (float*)d_out;

    const int N = in_sizes[0] / NF;
    const int E = in_sizes[1] / 2;
    const int* src = ei;
    const int* dst = ei + E;

    const int NB  = (N + 255) >> 8;                       // buckets of 256 nodes
    const int per = (E + NB - 1) / NB;
    const int cap = (per + (per >> 2) + 511) & ~511;      // +25% slack, 512-aligned

    // workspace layout (64B-aligned slices; no aliasing)
    char* ws = (char*)d_ws;
    size_t o = 0;
    auto alloc = [&](size_t bytes) {
        o = (o + 63) & ~(size_t)63;
        void* p = ws + o;
        o += bytes;
        return p;
    };
    int*    cnt_tot    = (int*)alloc((size_t)N * 4);
    int*    rowptr_tot = (int*)alloc((size_t)N * 4);
    float*  dinv       = (float*)alloc((size_t)N * 4);
    int*    bcur       = (int*)alloc((size_t)NBMAX * 4);
    int*    bbase      = (int*)alloc((size_t)NBMAX * 4);
    int*    esrc       = (int*)alloc((size_t)E * 4);            // 6.4 MB
    __half* h1         = (__half*)alloc((size_t)N * NH * 2);    // 12.8 MB fp16
    __half2* g         = (__half2*)alloc((size_t)N * NC * 2);   // 3.2 MB fp16
    int*    binned     = (int*)alloc((size_t)NB * cap * 4);     // ~9 MB

    int nbin = (E + BTILE - 1) / BTILE;

    k_binit<<<(NB + 255) / 256, 256, 0, stream>>>(bcur, NB, cap);
    k_bin<<<nbin, 256, 0, stream>>>(src, dst, bcur, binned, E, NB);
    k_scanb<<<1, 512, 0, stream>>>(bcur, bbase, NB, cap);
    k_prep<<<NB, 256, 0, stream>>>(binned, bcur, bbase, cnt_tot, rowptr_tot, dinv, esrc, cap, N);

    k_gemm1<<<(N + 63) / 64, 256, 0, stream>>>(x, W1, h1, N);
    k_agg1f<<<2048, 256, 0, stream>>>(h1, dinv, rowptr_tot, cnt_tot, esrc, b1, W2, g, N);
    k_agg2v<<<(N + 31) / 32, 256, 0, stream>>>(g, dinv, rowptr_tot, cnt_tot, esrc, b2, out, N);
}

// Round 3
// 301.645 us; speedup vs baseline: 1.1251x; 1.0370x over previous
//
#include <hip/hip_runtime.h>
#include <hip/hip_bf16.h>
#include <hip/hip_fp16.h>
#include <math.h>

#define NF 256
#define NH 64
#define NC 16
#define NBMAX 512      // max buckets (N/256 <= 512 -> N <= 131072)
#define BTILE 4096     // edges per bin block
#define PCAP 6144      // LDS staging capacity in k_prep (bucket edges ~4096+-64)

typedef __attribute__((ext_vector_type(8))) __bf16 bf16x8;
typedef __attribute__((ext_vector_type(4))) float f32x4;
typedef __attribute__((ext_vector_type(8))) short short8;

__device__ __forceinline__ unsigned short f2bf(float v) {   // RNE fp32->bf16
    unsigned u = __float_as_uint(v);
    unsigned r = u + 0x7fffu + ((u >> 16) & 1u);
    return (unsigned short)(r >> 16);
}
__device__ __forceinline__ float bf2f(unsigned short s) {
    return __uint_as_float(((unsigned)s) << 16);
}

// ---------------- bucket cursor init: bcur[b] = b*cap ----------------
__global__ void k_binit(int* __restrict__ bcur, int NB, int cap) {
    int b = blockIdx.x * 256 + threadIdx.x;
    if (b < NB) bcur[b] = b * cap;
}

// ---------------- FUSED: gemm1 (blocks < nGemm) + edge binning (rest) ----------
// Independent work; bin's latency/atomic phase overlaps gemm1's MFMA phase.
__global__ __launch_bounds__(256) void k_bingemm1(const float* __restrict__ x,
                                                  const float* __restrict__ W1,
                                                  __half* __restrict__ h1, int n,
                                                  const int* __restrict__ src,
                                                  const int* __restrict__ dst,
                                                  int* __restrict__ bcur,
                                                  int* __restrict__ binned,
                                                  int E, int NB, int nGemm) {
    __shared__ __align__(16) unsigned char smem[16384];
    int tid = threadIdx.x;
    if ((int)blockIdx.x < nGemm) {
        // ---- GEMM1 (MFMA bf16 hi/lo split): h1(fp16) = x @ W1 ----
        unsigned short* Ah = (unsigned short*)smem;
        unsigned short* Al = Ah + 2048;
        unsigned short* Bh = Al + 2048;
        unsigned short* Bl = Bh + 2048;
        int lane = tid & 63;
        int wid = tid >> 6;
        int m0 = blockIdx.x * 64;
        f32x4 acc[4] = {{0.f, 0.f, 0.f, 0.f}, {0.f, 0.f, 0.f, 0.f},
                        {0.f, 0.f, 0.f, 0.f}, {0.f, 0.f, 0.f, 0.f}};
        int bcol = tid & 63;
        int bkq = tid >> 6;
        int bIdx = ((bcol >> 4) * 512) + (((bkq << 4) | (bcol & 15)) * 8);
        for (int k0 = 0; k0 < NF; k0 += 32) {
            #pragma unroll
            for (int it = 0; it < 2; ++it) {
                int f = tid + it * 256;
                int m = f >> 3;
                int g = f & 7;
                int node = m0 + m;
                float4 xv = make_float4(0.f, 0.f, 0.f, 0.f);
                if (node < n) xv = *(const float4*)&x[(size_t)node * NF + k0 + g * 4];
                ushort4 hi, lo;
                hi.x = f2bf(xv.x); lo.x = f2bf(xv.x - bf2f(hi.x));
                hi.y = f2bf(xv.y); lo.y = f2bf(xv.y - bf2f(hi.y));
                hi.z = f2bf(xv.z); lo.z = f2bf(xv.z - bf2f(hi.z));
                hi.w = f2bf(xv.w); lo.w = f2bf(xv.w - bf2f(hi.w));
                int aIdx = ((m >> 4) * 512) + ((((g >> 1) << 4) | (m & 15)) * 8) + (g & 1) * 4;
                *(ushort4*)&Ah[aIdx] = hi;
                *(ushort4*)&Al[aIdx] = lo;
            }
            {
                unsigned short hb[8], lb[8];
                #pragma unroll
                for (int j = 0; j < 8; ++j) {
                    float w = W1[(size_t)(k0 + bkq * 8 + j) * NH + bcol];
                    hb[j] = f2bf(w);
                    lb[j] = f2bf(w - bf2f(hb[j]));
                }
                #pragma unroll
                for (int j = 0; j < 8; ++j) { Bh[bIdx + j] = hb[j]; Bl[bIdx + j] = lb[j]; }
            }
            __syncthreads();
            bf16x8 ah = __builtin_bit_cast(bf16x8, *(short8*)&Ah[wid * 512 + lane * 8]);
            bf16x8 al = __builtin_bit_cast(bf16x8, *(short8*)&Al[wid * 512 + lane * 8]);
            #pragma unroll
            for (int c = 0; c < 4; ++c) {
                bf16x8 bh = __builtin_bit_cast(bf16x8, *(short8*)&Bh[c * 512 + lane * 8]);
                bf16x8 bl = __builtin_bit_cast(bf16x8, *(short8*)&Bl[c * 512 + lane * 8]);
                acc[c] = __builtin_amdgcn_mfma_f32_16x16x32_bf16(ah, bh, acc[c], 0, 0, 0);
                acc[c] = __builtin_amdgcn_mfma_f32_16x16x32_bf16(al, bh, acc[c], 0, 0, 0);
                acc[c] = __builtin_amdgcn_mfma_f32_16x16x32_bf16(ah, bl, acc[c], 0, 0, 0);
            }
            __syncthreads();
        }
        int quad = lane >> 4;
        int cl = lane & 15;
        #pragma unroll
        for (int c = 0; c < 4; ++c) {
            #pragma unroll
            for (int r = 0; r < 4; ++r) {
                int row = m0 + wid * 16 + quad * 4 + r;
                if (row < n) h1[(size_t)row * NH + c * 16 + cl] = __float2half_rn(acc[c][r]);
            }
        }
    } else {
        // ---- edge binning by dst>>8; packed entry: src | (dst&255)<<24 ----
        int* histA = (int*)smem;
        int* histB = histA + NBMAX;
        int* gbase = histB + NBMAX;
        int e0 = (blockIdx.x - nGemm) * BTILE;
        for (int b = tid; b < NB; b += 256) { histA[b] = 0; histB[b] = 0; }
        __syncthreads();
        #pragma unroll
        for (int u = 0; u < BTILE / 256; ++u) {
            int i = e0 + u * 256 + tid;
            if (i < E) atomicAdd(&histA[dst[i] >> 8], 1);
        }
        __syncthreads();
        for (int b = tid; b < NB; b += 256) {
            int c = histA[b];
            gbase[b] = c ? atomicAdd(&bcur[b], c) : 0;
        }
        __syncthreads();
        #pragma unroll
        for (int u = 0; u < BTILE / 256; ++u) {
            int i = e0 + u * 256 + tid;
            if (i < E) {
                int d = dst[i];
                int b = d >> 8;
                int r = atomicAdd(&histB[b], 1);
                binned[gbase[b] + r] = src[i] | ((d & 255) << 24);
            }
        }
    }
}

// ---------------- prep: self-computed bucket base + hist + scan + scatter ------
// Writes rowcnt {rowptr,cnt} (int2), dinv, and scatters esrc. Reads binned once.
__global__ __launch_bounds__(256) void k_prep(const int* __restrict__ binned,
                                              const int* __restrict__ bcur,
                                              int2* __restrict__ rowcnt,
                                              float* __restrict__ dinv,
                                              int* __restrict__ esrc,
                                              int cap, int N, int NB) {
    __shared__ int eb[PCAP];
    __shared__ int h[256], sc[256], red[256];
    int b = blockIdx.x;
    int tid = threadIdx.x;
    int base = b * cap;
    int ne = bcur[b] - base;
    if (ne > PCAP) ne = PCAP;   // safety (never hit at this E/N)
    for (int i = tid; i < ne; i += 256) eb[i] = binned[base + i];
    // partial sums of preceding bucket sizes -> this bucket's global edge base
    int acc = 0;
    for (int i = tid; i < b; i += 256) acc += bcur[i] - i * cap;
    h[tid] = 0;
    red[tid] = acc;
    __syncthreads();
    for (int i = tid; i < ne; i += 256) atomicAdd(&h[(eb[i] >> 24) & 255], 1);
    __syncthreads();
    for (int off = 128; off > 0; off >>= 1) {
        if (tid < off) red[tid] += red[tid + off];
        __syncthreads();
    }
    int bbase_b = red[0];
    int c = h[tid];
    sc[tid] = c;
    __syncthreads();
    for (int off = 1; off < 256; off <<= 1) {
        int add = (tid >= off) ? sc[tid - off] : 0;
        __syncthreads();
        sc[tid] += add;
        __syncthreads();
    }
    int rp = bbase_b + sc[tid] - c;       // exclusive, bucket-major
    int v = (b << 8) + tid;
    if (v < N) {
        rowcnt[v] = make_int2(rp, c);
        dinv[v] = rsqrtf((float)(c + 1));
    }
    sc[tid] = rp;                         // reuse as scatter cursor
    __syncthreads();
    for (int i = tid; i < ne; i += 256) {
        int pk = eb[i];
        int pos = atomicAdd(&sc[(pk >> 24) & 255], 1);
        esrc[pos] = pk & 0x00FFFFFF;
    }
}

// ---------------- wfill: ew[i] = {src, dinv[src]} — kills dependent gathers ----
__global__ __launch_bounds__(256) void k_wfill(const int* __restrict__ esrc,
                                               const float* __restrict__ dinv,
                                               int2* __restrict__ ew, int E) {
    int i = blockIdx.x * 256 + threadIdx.x;
    int stride = gridDim.x * 256;
    for (; i < E; i += stride) {
        int s = esrc[i];
        ew[i] = make_int2(s, __float_as_int(dinv[s]));
    }
}

// ---------------- agg1 + bias + relu + FUSED GEMM2 -> g(fp16), DUAL-NODE -------
// NO shuffles in main loop: lane (es,fl) broadcast-loads its edge record
// directly (8 distinct addrs/wave) and gathers its h1 row slice. Edge batches
// software-pipelined one iteration ahead -> 4 independent gathers in flight.
// es = lane>>3 (edge slot / class pair), fl = lane&7 (features [8fl,8fl+8)).
__global__ __launch_bounds__(256) void k_agg1f(const __half* __restrict__ h1,
                                               const float* __restrict__ dinv,
                                               const int2* __restrict__ rowcnt,
                                               const int2* __restrict__ ew,
                                               const float* __restrict__ b1,
                                               const float* __restrict__ W2,
                                               __half2* __restrict__ g, int n) {
    int lane = threadIdx.x & 63;
    int wid = threadIdx.x >> 6;
    int es = lane >> 3;
    int fl = lane & 7;
    float2 w2[8];
    float b1r[8];
    #pragma unroll
    for (int k = 0; k < 8; ++k) {
        w2[k] = *(const float2*)&W2[(size_t)(8 * fl + k) * NC + 2 * es];
        b1r[k] = b1[8 * fl + k];
    }
    int pairs = (n + 1) >> 1;
    int stride = gridDim.x * 4;
    for (int p = blockIdx.x * 4 + wid; p < pairs; p += stride) {
        int v0 = 2 * p;
        int v1 = v0 + 1;
        bool val1 = v1 < n;
        int beg0, c0, beg1, c1;
        float dv0, dv1;
        if (val1) {
            int4 rc = *(const int4*)&rowcnt[v0];     // v0 even -> 16B aligned
            beg0 = rc.x; c0 = rc.y; beg1 = rc.z; c1 = rc.w;
            float2 dd = *(const float2*)&dinv[v0];
            dv0 = dd.x; dv1 = dd.y;
        } else {
            int2 rc = rowcnt[v0];
            beg0 = rc.x; c0 = rc.y; beg1 = 0; c1 = 0;
            dv0 = dinv[v0]; dv1 = 0.f;
        }
        // prefetch first edge batch (broadcast int2 loads; ew[0] safe pad)
        int i0 = es, i1 = 8 + es;
        int2 eA0 = ew[i0 < c0 ? beg0 + i0 : 0];
        int2 eA1 = ew[i1 < c0 ? beg0 + i1 : 0];
        int2 eB0 = ew[i0 < c1 ? beg1 + i0 : 0];
        int2 eB1 = ew[i1 < c1 ? beg1 + i1 : 0];
        float a0[8] = {0.f, 0.f, 0.f, 0.f, 0.f, 0.f, 0.f, 0.f};
        float a1[8] = {0.f, 0.f, 0.f, 0.f, 0.f, 0.f, 0.f, 0.f};
        {   // self-loops (weight only on es==0; overlaps the ew prefetch)
            float sw0 = (es == 0) ? dv0 * dv0 : 0.f;
            float sw1 = (es == 0) ? dv1 * dv1 : 0.f;
            uint4 q0 = *(const uint4*)&h1[(size_t)v0 * NH + 8 * fl];
            uint4 q1 = *(const uint4*)&h1[(size_t)(val1 ? v1 : v0) * NH + 8 * fl];
            const __half2* ph0 = (const __half2*)&q0;
            const __half2* ph1 = (const __half2*)&q1;
            #pragma unroll
            for (int q = 0; q < 4; ++q) {
                float2 f0 = __half22float2(ph0[q]);
                float2 f1 = __half22float2(ph1[q]);
                a0[2 * q]     = fmaf(sw0, f0.x, a0[2 * q]);
                a0[2 * q + 1] = fmaf(sw0, f0.y, a0[2 * q + 1]);
                a1[2 * q]     = fmaf(sw1, f1.x, a1[2 * q]);
                a1[2 * q + 1] = fmaf(sw1, f1.y, a1[2 * q + 1]);
            }
        }
        int cmax = c0 > c1 ? c0 : c1;
        for (int base = 0; base < cmax; base += 16) {
            int2 cA0 = eA0, cA1 = eA1, cB0 = eB0, cB1 = eB1;
            int nb = base + 16;
            if (nb < cmax) {   // prefetch next batch (hides ew latency)
                int j0 = nb + es, j1 = nb + 8 + es;
                eA0 = ew[j0 < c0 ? beg0 + j0 : 0];
                eA1 = ew[j1 < c0 ? beg0 + j1 : 0];
                eB0 = ew[j0 < c1 ? beg1 + j0 : 0];
                eB1 = ew[j1 < c1 ? beg1 + j1 : 0];
            }
            int e0 = base + es, e1 = base + 8 + es;
            float wA0 = (e0 < c0) ? __int_as_float(cA0.y) * dv0 : 0.f;
            float wA1 = (e1 < c0) ? __int_as_float(cA1.y) * dv0 : 0.f;
            float wB0 = (e0 < c1) ? __int_as_float(cB0.y) * dv1 : 0.f;
            float wB1 = (e1 < c1) ? __int_as_float(cB1.y) * dv1 : 0.f;
            uint4 pA0 = *(const uint4*)&h1[(size_t)cA0.x * NH + 8 * fl];
            uint4 pA1 = *(const uint4*)&h1[(size_t)cA1.x * NH + 8 * fl];
            uint4 pB0 = *(const uint4*)&h1[(size_t)cB0.x * NH + 8 * fl];
            uint4 pB1 = *(const uint4*)&h1[(size_t)cB1.x * NH + 8 * fl];
            const __half2* qA0 = (const __half2*)&pA0;
            const __half2* qA1 = (const __half2*)&pA1;
            const __half2* qB0 = (const __half2*)&pB0;
            const __half2* qB1 = (const __half2*)&pB1;
            #pragma unroll
            for (int q = 0; q < 4; ++q) {
                float2 fA0 = __half22float2(qA0[q]);
                float2 fA1 = __half22float2(qA1[q]);
                a0[2 * q]     = fmaf(wA0, fA0.x, a0[2 * q]);
                a0[2 * q + 1] = fmaf(wA0, fA0.y, a0[2 * q + 1]);
                a0[2 * q]     = fmaf(wA1, fA1.x, a0[2 * q]);
                a0[2 * q + 1] = fmaf(wA1, fA1.y, a0[2 * q + 1]);
                float2 fB0 = __half22float2(qB0[q]);
                float2 fB1 = __half22float2(qB1[q]);
                a1[2 * q]     = fmaf(wB0, fB0.x, a1[2 * q]);
                a1[2 * q + 1] = fmaf(wB0, fB0.y, a1[2 * q + 1]);
                a1[2 * q]     = fmaf(wB1, fB1.x, a1[2 * q]);
                a1[2 * q + 1] = fmaf(wB1, fB1.y, a1[2 * q + 1]);
            }
        }
        // reduce partials across the 8 edge-slots (xor 8,16,32) — ILP-2
        #pragma unroll
        for (int m = 8; m < 64; m <<= 1) {
            #pragma unroll
            for (int k = 0; k < 8; ++k) {
                a0[k] += __shfl_xor(a0[k], m);
                a1[k] += __shfl_xor(a1[k], m);
            }
        }
        // bias + relu + fused GEMM2 partials (2 classes per lane, both nodes)
        float p00 = 0.f, p01 = 0.f, p10 = 0.f, p11 = 0.f;
        #pragma unroll
        for (int k = 0; k < 8; ++k) {
            float h0 = fmaxf(a0[k] + b1r[k], 0.f);
            float h1v = fmaxf(a1[k] + b1r[k], 0.f);
            p00 = fmaf(h0, w2[k].x, p00);
            p01 = fmaf(h0, w2[k].y, p01);
            p10 = fmaf(h1v, w2[k].x, p10);
            p11 = fmaf(h1v, w2[k].y, p11);
        }
        #pragma unroll
        for (int m = 1; m < 8; m <<= 1) {   // reduce over fl (xor 1,2,4)
            p00 += __shfl_xor(p00, m);
            p01 += __shfl_xor(p01, m);
            p10 += __shfl_xor(p10, m);
            p11 += __shfl_xor(p11, m);
        }
        if (fl == 0) {
            g[(size_t)v0 * 8 + es] = __floats2half2_rn(p00, p01);
            if (val1) g[(size_t)v1 * 8 + es] = __floats2half2_rn(p10, p11);
        }
    }
}

// ---------------- agg2 + bias + log_softmax: 8-lane group/node, direct loads ---
// g table fp16 (3.2 MB, L2-resident). Lane cl owns class pair (2cl, 2cl+1).
// Per edge: one broadcast ew load + one gather; 8 independent chains unrolled.
__global__ __launch_bounds__(256) void k_agg2v(const __half2* __restrict__ g,
                                               const float* __restrict__ dinv,
                                               const int2* __restrict__ rowcnt,
                                               const int2* __restrict__ ew,
                                               const float* __restrict__ b2,
                                               float* __restrict__ out, int n) {
    int v = blockIdx.x * 32 + (threadIdx.x >> 3);
    int cl = threadIdx.x & 7;
    if (v >= n) return;
    float dv = dinv[v];
    int2 rc = rowcnt[v];
    float2 a;
    {
        float2 f = __half22float2(g[(size_t)v * 8 + cl]);
        float sw = dv * dv;
        a.x = sw * f.x;
        a.y = sw * f.y;
    }
    int beg = rc.x, cnt = rc.y;
    for (int base = 0; base < cnt; base += 8) {
        #pragma unroll
        for (int u = 0; u < 8; ++u) {
            int ei = base + u;
            int2 e = ew[ei < cnt ? beg + ei : 0];
            float w = (ei < cnt) ? __int_as_float(e.y) * dv : 0.f;
            float2 f = __half22float2(g[(size_t)e.x * 8 + cl]);
            a.x = fmaf(w, f.x, a.x);
            a.y = fmaf(w, f.y, a.y);
        }
    }
    a.x += b2[2 * cl];
    a.y += b2[2 * cl + 1];
    float m = fmaxf(a.x, a.y);
    #pragma unroll
    for (int mask = 1; mask < 8; mask <<= 1) m = fmaxf(m, __shfl_xor(m, mask, 8));
    float ex = __expf(a.x - m) + __expf(a.y - m);
    #pragma unroll
    for (int mask = 1; mask < 8; mask <<= 1) ex += __shfl_xor(ex, mask, 8);
    float ls = m + __logf(ex);
    *(float2*)&out[(size_t)v * NC + 2 * cl] = make_float2(a.x - ls, a.y - ls);
}

extern "C" void kernel_launch(void* const* d_in, const int* in_sizes, int n_in,
                              void* d_out, int out_size, void* d_ws, size_t ws_size,
                              hipStream_t stream) {
    const float* x  = (const float*)d_in[0];
    const int*   ei = (const int*)d_in[1];
    const float* W1 = (const float*)d_in[2];
    const float* b1 = (const float*)d_in[3];
    const float* W2 = (const float*)d_in[4];
    const float* b2 = (const float*)d_in[5];
    float* out = (float*)d_out;

    const int N = in_sizes[0] / NF;
    const int E = in_sizes[1] / 2;
    const int* src = ei;
    const int* dst = ei + E;

    const int NB  = (N + 255) >> 8;                       // buckets of 256 nodes
    const int per = (E + NB - 1) / NB;
    const int cap = (per + (per >> 2) + 511) & ~511;      // +25% slack, 512-aligned

    // workspace layout (64B-aligned slices; no aliasing)
    char* ws = (char*)d_ws;
    size_t o = 0;
    auto alloc = [&](size_t bytes) {
        o = (o + 63) & ~(size_t)63;
        void* p = ws + o;
        o += bytes;
        return p;
    };
    int2*   rowcnt = (int2*)alloc((size_t)N * 8);
    float*  dinv   = (float*)alloc((size_t)N * 4);
    int*    bcur   = (int*)alloc((size_t)NBMAX * 4);
    int*    esrc   = (int*)alloc((size_t)E * 4);            // 6.4 MB
    int2*   ew     = (int2*)alloc((size_t)E * 8);           // 12.8 MB {src,dinv[src]}
    __half* h1     = (__half*)alloc((size_t)N * NH * 2);    // 12.8 MB fp16
    __half2* g     = (__half2*)alloc((size_t)N * NC * 2);   // 3.2 MB fp16
    int*    binned = (int*)alloc((size_t)NB * cap * 4);     // ~8 MB

    int nbin = (E + BTILE - 1) / BTILE;
    int nGemm = (N + 63) / 64;

    k_binit<<<(NB + 255) / 256, 256, 0, stream>>>(bcur, NB, cap);
    k_bingemm1<<<nGemm + nbin, 256, 0, stream>>>(x, W1, h1, N, src, dst, bcur, binned,
                                                 E, NB, nGemm);
    k_prep<<<NB, 256, 0, stream>>>(binned, bcur, rowcnt, dinv, esrc, cap, N, NB);
    k_wfill<<<2048, 256, 0, stream>>>(esrc, dinv, ew, E);
    k_agg1f<<<2048, 256, 0, stream>>>(h1, dinv, rowcnt, ew, b1, W2, g, N);
    k_agg2v<<<(N + 31) / 32, 256, 0, stream>>>(g, dinv, rowcnt, ew, b2, out, N);
}